// Round 2
// baseline (419.795 us; speedup 1.0000x reference)
//
#include <hip/hip_runtime.h>
#include <stdint.h>
#include <stddef.h>

#define HEADS 8
#define DH 32
#define DMODEL 256
#define LN_EPS 1e-5f

typedef unsigned short u16;
typedef __bf16 bf16x8 __attribute__((ext_vector_type(8)));
typedef unsigned short u16x8 __attribute__((ext_vector_type(8)));
typedef float f32x4 __attribute__((ext_vector_type(4)));

static __device__ __forceinline__ u16 f2bf(float f) {
    union { float f; uint32_t u; } v; v.f = f;
    return (u16)((v.u + 0x7fffu + ((v.u >> 16) & 1u)) >> 16);  // RNE
}
static __device__ __forceinline__ bf16x8 ldbf8(const u16* p) {
    return __builtin_bit_cast(bf16x8, *reinterpret_cast<const u16x8*>(p));
}

// ---------------- fp32 -> bf16 convert (row-major copy) ----------------
__global__ __launch_bounds__(256) void cvt_f32_bf16(const float* __restrict__ in,
                                                    u16* __restrict__ out, int n) {
    int i = (blockIdx.x * 256 + threadIdx.x) * 4;
    int stride = gridDim.x * 256 * 4;
    for (; i < n; i += stride) {
        float4 f = *reinterpret_cast<const float4*>(in + i);
        ushort4 o = make_ushort4(f2bf(f.x), f2bf(f.y), f2bf(f.z), f2bf(f.w));
        *reinterpret_cast<ushort4*>(out + i) = o;
    }
}

// ---------------- batched transpose + convert: W[K][N] -> Wt[N][K] bf16 ----------------
struct TDesc { const float* src; u16* dst; int K; int N; };
struct TArgs { TDesc d[10]; };

__global__ __launch_bounds__(256) void transpose_cvt(TArgs args) {
    TDesc d = args.d[blockIdx.y];
    const int ntx = d.N >> 5;
    const int tiles = (d.K >> 5) * ntx;
    if ((int)blockIdx.x >= tiles) return;
    const int tk = (blockIdx.x / ntx) << 5;
    const int tn = (blockIdx.x % ntx) << 5;
    __shared__ float t[32][33];
    const int lx = threadIdx.x & 31;
    const int ly = threadIdx.x >> 5;
#pragma unroll
    for (int i = 0; i < 4; ++i)
        t[ly + 8 * i][lx] = d.src[(size_t)(tk + ly + 8 * i) * d.N + tn + lx];
    __syncthreads();
#pragma unroll
    for (int i = 0; i < 4; ++i)
        d.dst[(size_t)(tn + ly + 8 * i) * d.K + tk + lx] = f2bf(t[lx][ly + 8 * i]);
}

// ---------------- MFMA GEMM: C[M][N] = A[M][K] @ B + bias ----------------
// A: bf16 [M][K] row-major. Bt: bf16 [N][K] (= B^T) row-major. bias: f32 [N].
// MODE 0: f32 out [M][N].  MODE 1: bf16 out [M][N].  MODE 2: bf16 out TRANSPOSED [N][M].
template<int MODE, bool RELU>
__global__ __launch_bounds__(256) void gemm_bias(
    const u16* __restrict__ A, const u16* __restrict__ Bt,
    const float* __restrict__ bias, void* __restrict__ Cout,
    int M, int N, int K, int ntm)
{
    const int lane = threadIdx.x & 63;
    const int wave = threadIdx.x >> 6;
    const int l15 = lane & 15, lhi = lane >> 4;
    const int tm = (blockIdx.x % ntm) * 128;
    const int tn = (blockIdx.x / ntm) * 64;
    const int wm = tm + wave * 32;

    const f32x4 z4 = {0.f, 0.f, 0.f, 0.f};
    f32x4 acc[2][4];
#pragma unroll
    for (int i = 0; i < 2; ++i)
#pragma unroll
        for (int j = 0; j < 4; ++j) acc[i][j] = z4;

    const u16* a0p = A + (size_t)(wm + l15) * K + lhi * 8;
    const u16* a1p = a0p + (size_t)16 * K;
    const u16* b0p = Bt + (size_t)(tn + l15) * K + lhi * 8;

    for (int k = 0; k < K; k += 32) {
        bf16x8 a0 = ldbf8(a0p + k);
        bf16x8 a1 = ldbf8(a1p + k);
#pragma unroll
        for (int j = 0; j < 4; ++j) {
            bf16x8 b = ldbf8(b0p + (size_t)j * 16 * K + k);
            acc[0][j] = __builtin_amdgcn_mfma_f32_16x16x32_bf16(a0, b, acc[0][j], 0, 0, 0);
            acc[1][j] = __builtin_amdgcn_mfma_f32_16x16x32_bf16(a1, b, acc[1][j], 0, 0, 0);
        }
    }

#pragma unroll
    for (int i = 0; i < 2; ++i) {
#pragma unroll
        for (int j = 0; j < 4; ++j) {
            const int col = tn + j * 16 + l15;
            const float bv = bias[col];
            const int row0 = wm + i * 16 + lhi * 4;
            if (MODE == 0) {
                float* C = (float*)Cout;
#pragma unroll
                for (int r = 0; r < 4; ++r) {
                    float v = acc[i][j][r] + bv;
                    if (RELU) v = fmaxf(v, 0.f);
                    C[(size_t)(row0 + r) * N + col] = v;
                }
            } else if (MODE == 1) {
                u16* C = (u16*)Cout;
#pragma unroll
                for (int r = 0; r < 4; ++r) {
                    float v = acc[i][j][r] + bv;
                    if (RELU) v = fmaxf(v, 0.f);
                    C[(size_t)(row0 + r) * N + col] = f2bf(v);
                }
            } else {  // MODE 2: transposed bf16: C[col][row]
                u16* C = (u16*)Cout;
                ushort4 o = make_ushort4(f2bf(acc[i][j][0] + bv), f2bf(acc[i][j][1] + bv),
                                         f2bf(acc[i][j][2] + bv), f2bf(acc[i][j][3] + bv));
                *reinterpret_cast<ushort4*>(C + (size_t)col * M + row0) = o;
            }
        }
    }
}

// ---------------- fused flash attention (swapped-QK^T, 16 q-rows/wave) ----------------
// Qb [B*Sq][256], Kb [B*Sk][256] bf16 row-major; Vt [256][MkTot] bf16 (V transposed);
// mask f32 [B][Sk]; Ob [B*Sq][256] bf16.
// Block = 4 waves x 16 q-rows = 64 q-rows of one (b,h). Grid = B*H*(Sq/64).
//
// S^T = mfma(A=K_tile, B=Q_frag): D[row=k=lhi*4+r (+j*16)][col=q=l15].
// Each lane owns 16 S-values of q-row l15 -> in-lane max tree + 2 shfl_xor(16,32).
// P^T written to per-wave LDS pt[q][k] as ushort4 (4 ds_write_b64/tile), PV A-frag
// read back as 2 ds_read_b128 (A[row=q=l15][k]), B-frag = V^T rows (contiguous).
__global__ __launch_bounds__(256) void attn_kernel(
    const u16* __restrict__ Qb, const u16* __restrict__ Kb,
    const u16* __restrict__ Vt, const float* __restrict__ mask,
    u16* __restrict__ Ob, int Sq, int Sk, int MkTot)
{
    const int wave = threadIdx.x >> 6;
    const int lane = threadIdx.x & 63;
    const int l15 = lane & 15, lhi = lane >> 4;
    const int nqc = Sq >> 6;               // 64-row chunks per (b,h)
    const int bh = blockIdx.x / nqc;
    const int qc = blockIdx.x % nqc;
    const int b = bh >> 3;
    const int h = bh & 7;
    const int colh = h * DH;
    const int qrow0 = b * Sq + (qc << 6) + wave * 16;

    __shared__ __align__(16) u16 pt[4][16][72];   // per-wave P^T, stride 144B

    const f32x4 z4 = {0.f, 0.f, 0.f, 0.f};
    // Q B-fragment: B[kk=lhi*8+c][q=l15] = Q[qrow0+l15][colh+lhi*8+c]
    const bf16x8 qf = ldbf8(Qb + (size_t)(qrow0 + l15) * DMODEL + colh + lhi * 8);

    f32x4 ctx[2] = {z4, z4};                // D[row=q=lhi*4+r][col=d=dt*16+l15]
    float m = -1e30f, ssum = 0.f;           // stats for q-row l15 (lane-partial sum)

    const float scale = 0.17677669529663687f;  // 1/sqrt(32)
    const float* mb = mask + (size_t)b * Sk;
    const u16* kbase = Kb + (size_t)(b * Sk) * DMODEL + colh + lhi * 8;
    const u16* vbase = Vt + (size_t)colh * MkTot + (size_t)b * Sk;

    for (int kt = 0; kt < Sk; kt += 64) {
        // ---- S^T = K @ Q^T : 4 MFMAs, dh=32 is one full K-step ----
        f32x4 s[4];
        __builtin_amdgcn_s_setprio(1);
#pragma unroll
        for (int j = 0; j < 4; ++j) {
            bf16x8 kf = ldbf8(kbase + (size_t)(kt + j * 16 + l15) * DMODEL);
            s[j] = __builtin_amdgcn_mfma_f32_16x16x32_bf16(kf, qf, z4, 0, 0, 0);
        }
        __builtin_amdgcn_s_setprio(0);

        // ---- scale + mask (mask index k = kt + j*16 + lhi*4 + r) ----
#pragma unroll
        for (int j = 0; j < 4; ++j) {
            float4 mk = *reinterpret_cast<const float4*>(mb + kt + j * 16 + lhi * 4);
            s[j][0] = s[j][0] * scale + mk.x;
            s[j][1] = s[j][1] * scale + mk.y;
            s[j][2] = s[j][2] * scale + mk.z;
            s[j][3] = s[j][3] * scale + mk.w;
        }

        // ---- row max: in-lane 16 -> cross-lhi (2 shfl) ----
        float mx = fmaxf(fmaxf(s[0][0], s[0][1]), fmaxf(s[0][2], s[0][3]));
#pragma unroll
        for (int j = 1; j < 4; ++j)
            mx = fmaxf(mx, fmaxf(fmaxf(s[j][0], s[j][1]), fmaxf(s[j][2], s[j][3])));
        mx = fmaxf(mx, __shfl_xor(mx, 16, 64));
        mx = fmaxf(mx, __shfl_xor(mx, 32, 64));

        // ---- defer-max (T13): only rescale when max grew by > 8 ----
        if (!__all(mx - m <= 8.0f)) {
            float mn = fmaxf(m, mx);
            float corr = __expf(m - mn);
            m = mn;
            ssum *= corr;
#pragma unroll
            for (int r = 0; r < 4; ++r) {
                float cc = __shfl(corr, lhi * 4 + r, 64);  // corr of q-row lhi*4+r
                ctx[0][r] *= cc;
                ctx[1][r] *= cc;
            }
        }

        // ---- P = exp(S - m), lane-partial sum ----
        float ps = 0.f;
#pragma unroll
        for (int j = 0; j < 4; ++j)
#pragma unroll
            for (int r = 0; r < 4; ++r) {
                float p = __expf(s[j][r] - m);
                s[j][r] = p;
                ps += p;
            }
        ssum += ps;

        // ---- P^T -> LDS (vector writes): pt[q=l15][k=j*16+lhi*4 .. +3] ----
        asm volatile("" ::: "memory");
#pragma unroll
        for (int j = 0; j < 4; ++j) {
            ushort4 w = make_ushort4(f2bf(s[j][0]), f2bf(s[j][1]), f2bf(s[j][2]), f2bf(s[j][3]));
            *reinterpret_cast<ushort4*>(&pt[wave][l15][j * 16 + lhi * 4]) = w;
        }
        asm volatile("" ::: "memory");

        // ---- ctx += P @ V : A-frag = pt rows (b128), B-frag = V^T rows ----
        __builtin_amdgcn_s_setprio(1);
#pragma unroll
        for (int ks = 0; ks < 2; ++ks) {
            bf16x8 pa = ldbf8(&pt[wave][l15][ks * 32 + lhi * 8]);
#pragma unroll
            for (int dt = 0; dt < 2; ++dt) {
                bf16x8 vf = ldbf8(vbase + (size_t)(dt * 16 + l15) * MkTot +
                                  kt + ks * 32 + lhi * 8);
                ctx[dt] = __builtin_amdgcn_mfma_f32_16x16x32_bf16(pa, vf, ctx[dt], 0, 0, 0);
            }
        }
        __builtin_amdgcn_s_setprio(0);
    }

    // ---- epilogue: total row sums (2 shfl), divide, store ----
    ssum += __shfl_xor(ssum, 16, 64);
    ssum += __shfl_xor(ssum, 32, 64);
#pragma unroll
    for (int r = 0; r < 4; ++r) {
        const float inv = 1.0f / __shfl(ssum, lhi * 4 + r, 64);
        const int row = qrow0 + lhi * 4 + r;
#pragma unroll
        for (int dt = 0; dt < 2; ++dt)
            Ob[(size_t)row * DMODEL + colh + dt * 16 + l15] = f2bf(ctx[dt][r] * inv);
    }
}

// ---------------- LayerNorm (fused residual add; optional second LN of 2*y) ----------------
template<bool DBL, bool WBF>
__global__ __launch_bounds__(256) void ln_kernel(
    const float* __restrict__ X, const float* __restrict__ Res,
    const float* __restrict__ g1p, const float* __restrict__ b1p,
    const float* __restrict__ g2p, const float* __restrict__ b2p,
    float* __restrict__ Of, u16* __restrict__ Oh)
{
    const int lane = threadIdx.x & 63;
    const int row = blockIdx.x * 4 + (threadIdx.x >> 6);
    const size_t base = (size_t)row * DMODEL + lane * 4;
    float4 x = *reinterpret_cast<const float4*>(X + base);
    float4 rr = *reinterpret_cast<const float4*>(Res + base);
    float v[4] = {x.x + rr.x, x.y + rr.y, x.z + rr.z, x.w + rr.w};
    float s = v[0] + v[1] + v[2] + v[3];
    float q = v[0] * v[0] + v[1] * v[1] + v[2] * v[2] + v[3] * v[3];
#pragma unroll
    for (int m = 1; m < 64; m <<= 1) { s += __shfl_xor(s, m, 64); q += __shfl_xor(q, m, 64); }
    float mean = s * (1.0f / DMODEL);
    float rstd = rsqrtf(fmaxf(q * (1.0f / DMODEL) - mean * mean, 0.f) + LN_EPS);
    float4 g = *reinterpret_cast<const float4*>(g1p + lane * 4);
    float4 bb = *reinterpret_cast<const float4*>(b1p + lane * 4);
    float y[4];
    y[0] = (v[0] - mean) * rstd * g.x + bb.x;
    y[1] = (v[1] - mean) * rstd * g.y + bb.y;
    y[2] = (v[2] - mean) * rstd * g.z + bb.z;
    y[3] = (v[3] - mean) * rstd * g.w + bb.w;
    if constexpr (DBL) {
#pragma unroll
        for (int k2 = 0; k2 < 4; ++k2) y[k2] *= 2.0f;
        float s2 = y[0] + y[1] + y[2] + y[3];
        float q2 = y[0] * y[0] + y[1] * y[1] + y[2] * y[2] + y[3] * y[3];
#pragma unroll
        for (int m = 1; m < 64; m <<= 1) { s2 += __shfl_xor(s2, m, 64); q2 += __shfl_xor(q2, m, 64); }
        float mean2 = s2 * (1.0f / DMODEL);
        float rstd2 = rsqrtf(fmaxf(q2 * (1.0f / DMODEL) - mean2 * mean2, 0.f) + LN_EPS);
        float4 g2 = *reinterpret_cast<const float4*>(g2p + lane * 4);
        float4 b2 = *reinterpret_cast<const float4*>(b2p + lane * 4);
        y[0] = (y[0] - mean2) * rstd2 * g2.x + b2.x;
        y[1] = (y[1] - mean2) * rstd2 * g2.y + b2.y;
        y[2] = (y[2] - mean2) * rstd2 * g2.z + b2.z;
        y[3] = (y[3] - mean2) * rstd2 * g2.w + b2.w;
    }
    *reinterpret_cast<float4*>(Of + base) = make_float4(y[0], y[1], y[2], y[3]);
    if constexpr (WBF) {
        ushort4 o = make_ushort4(f2bf(y[0]), f2bf(y[1]), f2bf(y[2]), f2bf(y[3]));
        *reinterpret_cast<ushort4*>(Oh + base) = o;
    }
}

// ---------------- host-side orchestration ----------------
extern "C" void kernel_launch(void* const* d_in, const int* in_sizes, int n_in,
                              void* d_out, int out_size, void* d_ws, size_t ws_size,
                              hipStream_t stream) {
    constexpr size_t MB = 1u << 20;
    if (ws_size < 70 * MB) return;

    const float* vis   = (const float*)d_in[0];
    const float* txt   = (const float*)d_in[1];
    const float* vmask = (const float*)d_in[2];
    const float* tmask = (const float*)d_in[3];
    const float* sa_wq = (const float*)d_in[4];  const float* sa_bq = (const float*)d_in[5];
    const float* sa_wk = (const float*)d_in[6];  const float* sa_bk = (const float*)d_in[7];
    const float* sa_wv = (const float*)d_in[8];  const float* sa_bv = (const float*)d_in[9];
    const float* sa_wo = (const float*)d_in[10]; const float* sa_bo = (const float*)d_in[11];
    const float* ca_wq = (const float*)d_in[12]; const float* ca_bq = (const float*)d_in[13];
    const float* ca_wk = (const float*)d_in[14]; const float* ca_bk = (const float*)d_in[15];
    const float* ca_wv = (const float*)d_in[16]; const float* ca_bv = (const float*)d_in[17];
    const float* ca_wo = (const float*)d_in[18]; const float* ca_bo = (const float*)d_in[19];
    const float* ln1_g = (const float*)d_in[20]; const float* ln1_b = (const float*)d_in[21];
    const float* ln2_g = (const float*)d_in[22]; const float* ln2_b = (const float*)d_in[23];
    const float* ln3_g = (const float*)d_in[24]; const float* ln3_b = (const float*)d_in[25];
    const float* ln4_g = (const float*)d_in[26]; const float* ln4_b = (const float*)d_in[27];
    const float* fc1_w = (const float*)d_in[28]; const float* fc1_b = (const float*)d_in[29];
    const float* fc2_w = (const float*)d_in[30]; const float* fc2_b = (const float*)d_in[31];

    const int B = 4, Sq = 2048, St = 1024;
    const int Mq = B * Sq;   // 8192
    const int Mt = B * St;   // 4096

    char* ws = (char*)d_ws;
    u16*   Xv_bf   = (u16*)(ws + 0);
    u16*   Xt_bf   = (u16*)(ws + 4 * MB);
    u16*   q_bf    = (u16*)(ws + 6 * MB);
    u16*   k_bf    = (u16*)(ws + 10 * MB);
    u16*   vt_bf   = (u16*)(ws + 14 * MB);
    u16*   ctx_bf  = (u16*)(ws + 18 * MB);
    u16*   ffn1_bf = (u16*)(ws + 0);
    float* attn_f  = (float*)(ws + 32 * MB);
    float* h1_f    = (float*)(ws + 40 * MB);
    u16*   h1_bf   = (u16*)(ws + 48 * MB);
    float* h3_f    = (float*)(ws + 52 * MB);
    u16*   h3_bf   = (u16*)(ws + 60 * MB);
    u16*   wts     = (u16*)(ws + 64 * MB);
    float* ffn2_f  = attn_f;

    u16* wq_t  = wts + 0 * 65536;
    u16* wk_t  = wts + 1 * 65536;
    u16* wv_t  = wts + 2 * 65536;
    u16* wo_t  = wts + 3 * 65536;
    u16* cwq_t = wts + 4 * 65536;
    u16* cwk_t = wts + 5 * 65536;
    u16* cwv_t = wts + 6 * 65536;
    u16* cwo_t = wts + 7 * 65536;
    u16* fc1_t = wts + 8 * 65536;
    u16* fc2_t = fc1_t + 2048 * 256;

    cvt_f32_bf16<<<2048, 256, 0, stream>>>(vis, Xv_bf, Mq * DMODEL);
    cvt_f32_bf16<<<1024, 256, 0, stream>>>(txt, Xt_bf, Mt * DMODEL);

    TArgs ta;
    ta.d[0] = {sa_wq, wq_t, 256, 256};  ta.d[1] = {sa_wk, wk_t, 256, 256};
    ta.d[2] = {sa_wv, wv_t, 256, 256};  ta.d[3] = {sa_wo, wo_t, 256, 256};
    ta.d[4] = {ca_wq, cwq_t, 256, 256}; ta.d[5] = {ca_wk, cwk_t, 256, 256};
    ta.d[6] = {ca_wv, cwv_t, 256, 256}; ta.d[7] = {ca_wo, cwo_t, 256, 256};
    ta.d[8] = {fc1_w, fc1_t, 256, 2048};
    ta.d[9] = {fc2_w, fc2_t, 2048, 256};
    transpose_cvt<<<dim3(512, 10), 256, 0, stream>>>(ta);

    auto gemm_grid = [](int M, int N) { return dim3((M / 128) * (N / 64)); };

    // self-attention
    gemm_bias<1, false><<<gemm_grid(Mq, 256), 256, 0, stream>>>(Xv_bf, wq_t, sa_bq, q_bf,  Mq, 256, 256, Mq / 128);
    gemm_bias<1, false><<<gemm_grid(Mq, 256), 256, 0, stream>>>(Xv_bf, wk_t, sa_bk, k_bf,  Mq, 256, 256, Mq / 128);
    gemm_bias<2, false><<<gemm_grid(Mq, 256), 256, 0, stream>>>(Xv_bf, wv_t, sa_bv, vt_bf, Mq, 256, 256, Mq / 128);
    attn_kernel<<<dim3(B * HEADS * (Sq / 64)), 256, 0, stream>>>(q_bf, k_bf, vt_bf, vmask, ctx_bf, Sq, Sq, Mq);
    gemm_bias<0, false><<<gemm_grid(Mq, 256), 256, 0, stream>>>(ctx_bf, wo_t, sa_bo, attn_f, Mq, 256, 256, Mq / 128);
    ln_kernel<false, true><<<dim3(Mq / 4), 256, 0, stream>>>(attn_f, vis, ln1_g, ln1_b, nullptr, nullptr, h1_f, h1_bf);

    // cross-attention
    gemm_bias<1, false><<<gemm_grid(Mq, 256), 256, 0, stream>>>(h1_bf, cwq_t, ca_bq, q_bf,  Mq, 256, 256, Mq / 128);
    gemm_bias<1, false><<<gemm_grid(Mt, 256), 256, 0, stream>>>(Xt_bf, cwk_t, ca_bk, k_bf,  Mt, 256, 256, Mt / 128);
    gemm_bias<2, false><<<gemm_grid(Mt, 256), 256, 0, stream>>>(Xt_bf, cwv_t, ca_bv, vt_bf, Mt, 256, 256, Mt / 128);
    attn_kernel<<<dim3(B * HEADS * (Sq / 64)), 256, 0, stream>>>(q_bf, k_bf, vt_bf, tmask, ctx_bf, Sq, St, Mt);
    gemm_bias<0, false><<<gemm_grid(Mq, 256), 256, 0, stream>>>(ctx_bf, cwo_t, ca_bo, attn_f, Mq, 256, 256, Mq / 128);
    ln_kernel<true, true><<<dim3(Mq / 4), 256, 0, stream>>>(attn_f, h1_f, ln2_g, ln2_b, ln3_g, ln3_b, h3_f, h3_bf);

    // FFN
    gemm_bias<1, true><<<gemm_grid(Mq, 2048), 256, 0, stream>>>(h3_bf, fc1_t, fc1_b, ffn1_bf, Mq, 2048, 256, Mq / 128);
    gemm_bias<0, false><<<gemm_grid(Mq, 256), 256, 0, stream>>>(ffn1_bf, fc2_t, fc2_b, ffn2_f, Mq, 256, 2048, Mq / 128);
    ln_kernel<false, false><<<dim3(Mq / 4), 256, 0, stream>>>(ffn2_f, h3_f, ln4_g, ln4_b, nullptr, nullptr, (float*)d_out, nullptr);
}

// Round 3
// 391.241 us; speedup vs baseline: 1.0730x; 1.0730x over previous
//
#include <hip/hip_runtime.h>
#include <stdint.h>
#include <stddef.h>

#define HEADS 8
#define DH 32
#define DMODEL 256
#define LN_EPS 1e-5f

typedef unsigned short u16;
typedef __bf16 bf16x8 __attribute__((ext_vector_type(8)));
typedef unsigned short u16x8 __attribute__((ext_vector_type(8)));
typedef float f32x4 __attribute__((ext_vector_type(4)));

static __device__ __forceinline__ u16 f2bf(float f) {
    union { float f; uint32_t u; } v; v.f = f;
    return (u16)((v.u + 0x7fffu + ((v.u >> 16) & 1u)) >> 16);  // RNE
}
static __device__ __forceinline__ bf16x8 ldbf8(const u16* p) {
    return __builtin_bit_cast(bf16x8, *reinterpret_cast<const u16x8*>(p));
}
static __device__ __forceinline__ bf16x8 cvt8(float4 a, float4 b) {
    bf16x8 r;
    r[0] = (__bf16)a.x; r[1] = (__bf16)a.y; r[2] = (__bf16)a.z; r[3] = (__bf16)a.w;
    r[4] = (__bf16)b.x; r[5] = (__bf16)b.y; r[6] = (__bf16)b.z; r[7] = (__bf16)b.w;
    return r;
}

// ---------------- batched transpose + convert: W[K][N] -> Wt[N][K] bf16 ----------------
struct TDesc { const float* src; u16* dst; int K; int N; };
struct TArgs { TDesc d[10]; };

__global__ __launch_bounds__(256) void transpose_cvt(TArgs args) {
    TDesc d = args.d[blockIdx.y];
    const int ntx = d.N >> 5;
    const int tiles = (d.K >> 5) * ntx;
    if ((int)blockIdx.x >= tiles) return;
    const int tk = (blockIdx.x / ntx) << 5;
    const int tn = (blockIdx.x % ntx) << 5;
    __shared__ float t[32][33];
    const int lx = threadIdx.x & 31;
    const int ly = threadIdx.x >> 5;
#pragma unroll
    for (int i = 0; i < 4; ++i)
        t[ly + 8 * i][lx] = d.src[(size_t)(tk + ly + 8 * i) * d.N + tn + lx];
    __syncthreads();
#pragma unroll
    for (int i = 0; i < 4; ++i)
        d.dst[(size_t)(tn + ly + 8 * i) * d.K + tk + lx] = f2bf(t[lx][ly + 8 * i]);
}

// ---------------- fused projection GEMM: f32 A -> up to 3 output slices ----------------
// A: f32 [M][256]. Wt: bf16 [NS*256][256] (W^T concat). Each 256-col slice has its
// own out buffer, bias, and mode (1 = bf16 [M][256] row-major, 2 = bf16 [256][M] transposed).
struct Slice { u16* out; const float* bias; int mode; };

__global__ __launch_bounds__(256) void gemm_xproj(
    const float* __restrict__ Af, const u16* __restrict__ Wt,
    Slice s0, Slice s1, Slice s2, int M, int ntm)
{
    const int lane = threadIdx.x & 63;
    const int wave = threadIdx.x >> 6;
    const int l15 = lane & 15, lhi = lane >> 4;
    const int tm = ((int)blockIdx.x % ntm) * 128;
    const int tn = ((int)blockIdx.x / ntm) * 64;
    const int wm = tm + wave * 32;
    const int sel = tn >> 8;
    const int tl = tn & 255;
    Slice sl = (sel == 0) ? s0 : (sel == 1 ? s1 : s2);

    const f32x4 z4 = {0.f, 0.f, 0.f, 0.f};
    f32x4 acc[2][4];
#pragma unroll
    for (int i = 0; i < 2; ++i)
#pragma unroll
        for (int j = 0; j < 4; ++j) acc[i][j] = z4;

    const float* ar0 = Af + (size_t)(wm + l15) * 256 + lhi * 8;
    const float* ar1 = ar0 + (size_t)16 * 256;
    const u16* b0p = Wt + (size_t)(tn + l15) * 256 + lhi * 8;

    float4 a00 = *(const float4*)(ar0), a01 = *(const float4*)(ar0 + 4);
    float4 a10 = *(const float4*)(ar1), a11 = *(const float4*)(ar1 + 4);
    bf16x8 b[4];
#pragma unroll
    for (int j = 0; j < 4; ++j) b[j] = ldbf8(b0p + (size_t)j * 16 * 256);

#pragma unroll
    for (int k = 32; k < 256; k += 32) {
        float4 n00 = *(const float4*)(ar0 + k), n01 = *(const float4*)(ar0 + k + 4);
        float4 n10 = *(const float4*)(ar1 + k), n11 = *(const float4*)(ar1 + k + 4);
        bf16x8 bn[4];
#pragma unroll
        for (int j = 0; j < 4; ++j) bn[j] = ldbf8(b0p + (size_t)j * 16 * 256 + k);
        bf16x8 a0 = cvt8(a00, a01), a1 = cvt8(a10, a11);
#pragma unroll
        for (int j = 0; j < 4; ++j) {
            acc[0][j] = __builtin_amdgcn_mfma_f32_16x16x32_bf16(a0, b[j], acc[0][j], 0, 0, 0);
            acc[1][j] = __builtin_amdgcn_mfma_f32_16x16x32_bf16(a1, b[j], acc[1][j], 0, 0, 0);
        }
        a00 = n00; a01 = n01; a10 = n10; a11 = n11;
#pragma unroll
        for (int j = 0; j < 4; ++j) b[j] = bn[j];
    }
    {
        bf16x8 a0 = cvt8(a00, a01), a1 = cvt8(a10, a11);
#pragma unroll
        for (int j = 0; j < 4; ++j) {
            acc[0][j] = __builtin_amdgcn_mfma_f32_16x16x32_bf16(a0, b[j], acc[0][j], 0, 0, 0);
            acc[1][j] = __builtin_amdgcn_mfma_f32_16x16x32_bf16(a1, b[j], acc[1][j], 0, 0, 0);
        }
    }

#pragma unroll
    for (int i = 0; i < 2; ++i) {
#pragma unroll
        for (int j = 0; j < 4; ++j) {
            const int col = tl + j * 16 + l15;
            const float bv = sl.bias[col];
            const int row0 = wm + i * 16 + lhi * 4;
            if (sl.mode == 1) {
#pragma unroll
                for (int r = 0; r < 4; ++r)
                    sl.out[(size_t)(row0 + r) * 256 + col] = f2bf(acc[i][j][r] + bv);
            } else {
                ushort4 o = make_ushort4(f2bf(acc[i][j][0] + bv), f2bf(acc[i][j][1] + bv),
                                         f2bf(acc[i][j][2] + bv), f2bf(acc[i][j][3] + bv));
                *reinterpret_cast<ushort4*>(sl.out + (size_t)col * M + row0) = o;
            }
        }
    }
}

// ---------------- MFMA GEMM: C[M][N] = A[M][K] @ B + bias (distance-1 prefetch) ----------------
// MODE 0: f32 out [M][N].  MODE 1: bf16 out [M][N].
template<int MODE, bool RELU>
__global__ __launch_bounds__(256) void gemm_bias(
    const u16* __restrict__ A, const u16* __restrict__ Bt,
    const float* __restrict__ bias, void* __restrict__ Cout,
    int M, int N, int K, int ntm)
{
    const int lane = threadIdx.x & 63;
    const int wave = threadIdx.x >> 6;
    const int l15 = lane & 15, lhi = lane >> 4;
    const int tm = ((int)blockIdx.x % ntm) * 128;
    const int tn = ((int)blockIdx.x / ntm) * 64;
    const int wm = tm + wave * 32;

    const f32x4 z4 = {0.f, 0.f, 0.f, 0.f};
    f32x4 acc[2][4];
#pragma unroll
    for (int i = 0; i < 2; ++i)
#pragma unroll
        for (int j = 0; j < 4; ++j) acc[i][j] = z4;

    const u16* a0p = A + (size_t)(wm + l15) * K + lhi * 8;
    const u16* a1p = a0p + (size_t)16 * K;
    const u16* b0p = Bt + (size_t)(tn + l15) * K + lhi * 8;

    bf16x8 a0 = ldbf8(a0p), a1 = ldbf8(a1p);
    bf16x8 b[4];
#pragma unroll
    for (int j = 0; j < 4; ++j) b[j] = ldbf8(b0p + (size_t)j * 16 * K);

    for (int k = 32; k < K; k += 32) {
        bf16x8 a0n = ldbf8(a0p + k), a1n = ldbf8(a1p + k);
        bf16x8 bn[4];
#pragma unroll
        for (int j = 0; j < 4; ++j) bn[j] = ldbf8(b0p + (size_t)j * 16 * K + k);
#pragma unroll
        for (int j = 0; j < 4; ++j) {
            acc[0][j] = __builtin_amdgcn_mfma_f32_16x16x32_bf16(a0, b[j], acc[0][j], 0, 0, 0);
            acc[1][j] = __builtin_amdgcn_mfma_f32_16x16x32_bf16(a1, b[j], acc[1][j], 0, 0, 0);
        }
        a0 = a0n; a1 = a1n;
#pragma unroll
        for (int j = 0; j < 4; ++j) b[j] = bn[j];
    }
#pragma unroll
    for (int j = 0; j < 4; ++j) {
        acc[0][j] = __builtin_amdgcn_mfma_f32_16x16x32_bf16(a0, b[j], acc[0][j], 0, 0, 0);
        acc[1][j] = __builtin_amdgcn_mfma_f32_16x16x32_bf16(a1, b[j], acc[1][j], 0, 0, 0);
    }

#pragma unroll
    for (int i = 0; i < 2; ++i) {
#pragma unroll
        for (int j = 0; j < 4; ++j) {
            const int col = tn + j * 16 + l15;
            const float bv = bias[col];
            const int row0 = wm + i * 16 + lhi * 4;
            if (MODE == 0) {
                float* C = (float*)Cout;
#pragma unroll
                for (int r = 0; r < 4; ++r) {
                    float v = acc[i][j][r] + bv;
                    if (RELU) v = fmaxf(v, 0.f);
                    C[(size_t)(row0 + r) * N + col] = v;
                }
            } else {
                u16* C = (u16*)Cout;
#pragma unroll
                for (int r = 0; r < 4; ++r) {
                    float v = acc[i][j][r] + bv;
                    if (RELU) v = fmaxf(v, 0.f);
                    C[(size_t)(row0 + r) * N + col] = f2bf(v);
                }
            }
        }
    }
}

// ---------------- fused flash attention (swapped-QK^T, K/V register prefetch) ----------------
// Qb [B*Sq][256], Kb [B*Sk][256] bf16; Vt [256][MkTot] bf16 (V^T); mask f32 [B][Sk];
// Ob [B*Sq][256] bf16. Block = 4 waves x 16 q-rows. Grid = B*H*(Sq/64).
__global__ __launch_bounds__(256) void attn_kernel(
    const u16* __restrict__ Qb, const u16* __restrict__ Kb,
    const u16* __restrict__ Vt, const float* __restrict__ mask,
    u16* __restrict__ Ob, int Sq, int Sk, int MkTot)
{
    const int wave = threadIdx.x >> 6;
    const int lane = threadIdx.x & 63;
    const int l15 = lane & 15, lhi = lane >> 4;
    const int nqc = Sq >> 6;
    const int bh = blockIdx.x / nqc;
    const int qc = blockIdx.x % nqc;
    const int b = bh >> 3;
    const int h = bh & 7;
    const int colh = h * DH;
    const int qrow0 = b * Sq + (qc << 6) + wave * 16;
    const int swz = (l15 & 8) << 1;     // XOR on u16 k-index: breaks row/row+8 bank aliasing

    __shared__ __align__(16) u16 pt[4][16][72];

    const f32x4 z4 = {0.f, 0.f, 0.f, 0.f};
    const bf16x8 qf = ldbf8(Qb + (size_t)(qrow0 + l15) * DMODEL + colh + lhi * 8);

    f32x4 ctx[2] = {z4, z4};
    float m = -1e30f, ssum = 0.f;

    const float scale = 0.17677669529663687f;  // 1/sqrt(32)
    const float* mb = mask + (size_t)b * Sk;
    const u16* kbase = Kb + (size_t)(b * Sk) * DMODEL + colh + lhi * 8;
    const u16* vbase = Vt + (size_t)colh * MkTot + (size_t)b * Sk;

    // preload tile 0 K/V fragments into registers
    bf16x8 kf[4], vf[4];
#pragma unroll
    for (int j = 0; j < 4; ++j)
        kf[j] = ldbf8(kbase + (size_t)(j * 16 + l15) * DMODEL);
#pragma unroll
    for (int ks = 0; ks < 2; ++ks)
#pragma unroll
        for (int dt = 0; dt < 2; ++dt)
            vf[ks * 2 + dt] = ldbf8(vbase + (size_t)(dt * 16 + l15) * MkTot + ks * 32 + lhi * 8);

    for (int kt = 0; kt < Sk; kt += 64) {
        // ---- S^T = K @ Q^T ----
        f32x4 s[4];
        __builtin_amdgcn_s_setprio(1);
#pragma unroll
        for (int j = 0; j < 4; ++j)
            s[j] = __builtin_amdgcn_mfma_f32_16x16x32_bf16(kf[j], qf, z4, 0, 0, 0);
        __builtin_amdgcn_s_setprio(0);

        // ---- prefetch next tile K/V (latency hides under softmax + LDS + PV) ----
        const int ktn = (kt + 64 < Sk) ? kt + 64 : kt;
        bf16x8 kn[4], vn[4];
#pragma unroll
        for (int j = 0; j < 4; ++j)
            kn[j] = ldbf8(kbase + (size_t)(ktn + j * 16 + l15) * DMODEL);
#pragma unroll
        for (int ks = 0; ks < 2; ++ks)
#pragma unroll
            for (int dt = 0; dt < 2; ++dt)
                vn[ks * 2 + dt] = ldbf8(vbase + (size_t)(dt * 16 + l15) * MkTot + ktn + ks * 32 + lhi * 8);

        // ---- scale + mask ----
#pragma unroll
        for (int j = 0; j < 4; ++j) {
            float4 mk = *reinterpret_cast<const float4*>(mb + kt + j * 16 + lhi * 4);
            s[j][0] = s[j][0] * scale + mk.x;
            s[j][1] = s[j][1] * scale + mk.y;
            s[j][2] = s[j][2] * scale + mk.z;
            s[j][3] = s[j][3] * scale + mk.w;
        }

        // ---- row max: in-lane 16 -> 2 shfl ----
        float mx = fmaxf(fmaxf(s[0][0], s[0][1]), fmaxf(s[0][2], s[0][3]));
#pragma unroll
        for (int j = 1; j < 4; ++j)
            mx = fmaxf(mx, fmaxf(fmaxf(s[j][0], s[j][1]), fmaxf(s[j][2], s[j][3])));
        mx = fmaxf(mx, __shfl_xor(mx, 16, 64));
        mx = fmaxf(mx, __shfl_xor(mx, 32, 64));

        // ---- defer-max (T13) ----
        if (!__all(mx - m <= 8.0f)) {
            float mn = fmaxf(m, mx);
            float corr = __expf(m - mn);
            m = mn;
            ssum *= corr;
#pragma unroll
            for (int r = 0; r < 4; ++r) {
                float cc = __shfl(corr, lhi * 4 + r, 64);
                ctx[0][r] *= cc;
                ctx[1][r] *= cc;
            }
        }

        // ---- P = exp(S - m) ----
        float ps = 0.f;
#pragma unroll
        for (int j = 0; j < 4; ++j)
#pragma unroll
            for (int r = 0; r < 4; ++r) {
                float p = __expf(s[j][r] - m);
                s[j][r] = p;
                ps += p;
            }
        ssum += ps;

        // ---- P^T -> LDS (swizzled ushort4 writes) ----
        asm volatile("" ::: "memory");
#pragma unroll
        for (int j = 0; j < 4; ++j) {
            ushort4 w = make_ushort4(f2bf(s[j][0]), f2bf(s[j][1]), f2bf(s[j][2]), f2bf(s[j][3]));
            *reinterpret_cast<ushort4*>(&pt[wave][l15][(j * 16 + lhi * 4) ^ swz]) = w;
        }
        asm volatile("" ::: "memory");

        // ---- ctx += P @ V (V already in regs) ----
        __builtin_amdgcn_s_setprio(1);
#pragma unroll
        for (int ks = 0; ks < 2; ++ks) {
            bf16x8 pa = ldbf8(&pt[wave][l15][(ks * 32 + lhi * 8) ^ swz]);
#pragma unroll
            for (int dt = 0; dt < 2; ++dt)
                ctx[dt] = __builtin_amdgcn_mfma_f32_16x16x32_bf16(pa, vf[ks * 2 + dt], ctx[dt], 0, 0, 0);
        }
        __builtin_amdgcn_s_setprio(0);

#pragma unroll
        for (int j = 0; j < 4; ++j) { kf[j] = kn[j]; vf[j] = vn[j]; }
    }

    // ---- epilogue ----
    ssum += __shfl_xor(ssum, 16, 64);
    ssum += __shfl_xor(ssum, 32, 64);
#pragma unroll
    for (int r = 0; r < 4; ++r) {
        const float inv = 1.0f / __shfl(ssum, lhi * 4 + r, 64);
        const int row = qrow0 + lhi * 4 + r;
#pragma unroll
        for (int dt = 0; dt < 2; ++dt)
            Ob[(size_t)row * DMODEL + colh + dt * 16 + l15] = f2bf(ctx[dt][r] * inv);
    }
}

// ---------------- LayerNorm (fused residual add; optional second LN of 2*y) ----------------
template<bool DBL, bool WBF>
__global__ __launch_bounds__(256) void ln_kernel(
    const float* __restrict__ X, const float* __restrict__ Res,
    const float* __restrict__ g1p, const float* __restrict__ b1p,
    const float* __restrict__ g2p, const float* __restrict__ b2p,
    float* __restrict__ Of, u16* __restrict__ Oh)
{
    const int lane = threadIdx.x & 63;
    const int row = blockIdx.x * 4 + (threadIdx.x >> 6);
    const size_t base = (size_t)row * DMODEL + lane * 4;
    float4 x = *reinterpret_cast<const float4*>(X + base);
    float4 rr = *reinterpret_cast<const float4*>(Res + base);
    float v[4] = {x.x + rr.x, x.y + rr.y, x.z + rr.z, x.w + rr.w};
    float s = v[0] + v[1] + v[2] + v[3];
    float q = v[0] * v[0] + v[1] * v[1] + v[2] * v[2] + v[3] * v[3];
#pragma unroll
    for (int m = 1; m < 64; m <<= 1) { s += __shfl_xor(s, m, 64); q += __shfl_xor(q, m, 64); }
    float mean = s * (1.0f / DMODEL);
    float rstd = rsqrtf(fmaxf(q * (1.0f / DMODEL) - mean * mean, 0.f) + LN_EPS);
    float4 g = *reinterpret_cast<const float4*>(g1p + lane * 4);
    float4 bb = *reinterpret_cast<const float4*>(b1p + lane * 4);
    float y[4];
    y[0] = (v[0] - mean) * rstd * g.x + bb.x;
    y[1] = (v[1] - mean) * rstd * g.y + bb.y;
    y[2] = (v[2] - mean) * rstd * g.z + bb.z;
    y[3] = (v[3] - mean) * rstd * g.w + bb.w;
    if constexpr (DBL) {
#pragma unroll
        for (int k2 = 0; k2 < 4; ++k2) y[k2] *= 2.0f;
        float s2 = y[0] + y[1] + y[2] + y[3];
        float q2 = y[0] * y[0] + y[1] * y[1] + y[2] * y[2] + y[3] * y[3];
#pragma unroll
        for (int m = 1; m < 64; m <<= 1) { s2 += __shfl_xor(s2, m, 64); q2 += __shfl_xor(q2, m, 64); }
        float mean2 = s2 * (1.0f / DMODEL);
        float rstd2 = rsqrtf(fmaxf(q2 * (1.0f / DMODEL) - mean2 * mean2, 0.f) + LN_EPS);
        float4 g2 = *reinterpret_cast<const float4*>(g2p + lane * 4);
        float4 b2 = *reinterpret_cast<const float4*>(b2p + lane * 4);
        y[0] = (y[0] - mean2) * rstd2 * g2.x + b2.x;
        y[1] = (y[1] - mean2) * rstd2 * g2.y + b2.y;
        y[2] = (y[2] - mean2) * rstd2 * g2.z + b2.z;
        y[3] = (y[3] - mean2) * rstd2 * g2.w + b2.w;
    }
    *reinterpret_cast<float4*>(Of + base) = make_float4(y[0], y[1], y[2], y[3]);
    if constexpr (WBF) {
        ushort4 o = make_ushort4(f2bf(y[0]), f2bf(y[1]), f2bf(y[2]), f2bf(y[3]));
        *reinterpret_cast<ushort4*>(Oh + base) = o;
    }
}

// ---------------- host-side orchestration ----------------
extern "C" void kernel_launch(void* const* d_in, const int* in_sizes, int n_in,
                              void* d_out, int out_size, void* d_ws, size_t ws_size,
                              hipStream_t stream) {
    constexpr size_t MB = 1u << 20;
    if (ws_size < 70 * MB) return;

    const float* vis   = (const float*)d_in[0];
    const float* txt   = (const float*)d_in[1];
    const float* vmask = (const float*)d_in[2];
    const float* tmask = (const float*)d_in[3];
    const float* sa_wq = (const float*)d_in[4];  const float* sa_bq = (const float*)d_in[5];
    const float* sa_wk = (const float*)d_in[6];  const float* sa_bk = (const float*)d_in[7];
    const float* sa_wv = (const float*)d_in[8];  const float* sa_bv = (const float*)d_in[9];
    const float* sa_wo = (const float*)d_in[10]; const float* sa_bo = (const float*)d_in[11];
    const float* ca_wq = (const float*)d_in[12]; const float* ca_bq = (const float*)d_in[13];
    const float* ca_wk = (const float*)d_in[14]; const float* ca_bk = (const float*)d_in[15];
    const float* ca_wv = (const float*)d_in[16]; const float* ca_bv = (const float*)d_in[17];
    const float* ca_wo = (const float*)d_in[18]; const float* ca_bo = (const float*)d_in[19];
    const float* ln1_g = (const float*)d_in[20]; const float* ln1_b = (const float*)d_in[21];
    const float* ln2_g = (const float*)d_in[22]; const float* ln2_b = (const float*)d_in[23];
    const float* ln3_g = (const float*)d_in[24]; const float* ln3_b = (const float*)d_in[25];
    const float* ln4_g = (const float*)d_in[26]; const float* ln4_b = (const float*)d_in[27];
    const float* fc1_w = (const float*)d_in[28]; const float* fc1_b = (const float*)d_in[29];
    const float* fc2_w = (const float*)d_in[30]; const float* fc2_b = (const float*)d_in[31];

    const int B = 4, Sq = 2048, St = 1024;
    const int Mq = B * Sq;   // 8192
    const int Mt = B * St;   // 4096

    char* ws = (char*)d_ws;
    u16*   q_bf    = (u16*)(ws + 6 * MB);
    u16*   k_bf    = (u16*)(ws + 10 * MB);
    u16*   vt_bf   = (u16*)(ws + 14 * MB);
    u16*   ctx_bf  = (u16*)(ws + 18 * MB);
    u16*   ffn1_bf = (u16*)(ws + 0);          // 32MB, overlaps (dead by FFN)
    float* attn_f  = (float*)(ws + 32 * MB);
    float* h1_f    = (float*)(ws + 40 * MB);
    u16*   h1_bf   = (u16*)(ws + 48 * MB);
    float* h3_f    = (float*)(ws + 52 * MB);
    u16*   h3_bf   = (u16*)(ws + 60 * MB);
    u16*   wts     = (u16*)(ws + 64 * MB);
    float* ffn2_f  = attn_f;

    u16* wqkv_t = wts;                        // [768][256]
    u16* wkv_t  = wqkv_t + 768 * 256;         // [512][256]
    u16* cwq_t  = wkv_t + 512 * 256;
    u16* wo_t   = cwq_t + 65536;
    u16* cwo_t  = wo_t + 65536;
    u16* fc1_t  = cwo_t + 65536;              // [2048][256]
    u16* fc2_t  = fc1_t + 2048 * 256;         // [256][2048]

    TArgs ta;
    ta.d[0] = {sa_wq, wqkv_t + 0 * 65536, 256, 256};
    ta.d[1] = {sa_wk, wqkv_t + 1 * 65536, 256, 256};
    ta.d[2] = {sa_wv, wqkv_t + 2 * 65536, 256, 256};
    ta.d[3] = {ca_wk, wkv_t + 0 * 65536, 256, 256};
    ta.d[4] = {ca_wv, wkv_t + 1 * 65536, 256, 256};
    ta.d[5] = {ca_wq, cwq_t, 256, 256};
    ta.d[6] = {sa_wo, wo_t, 256, 256};
    ta.d[7] = {ca_wo, cwo_t, 256, 256};
    ta.d[8] = {fc1_w, fc1_t, 256, 2048};
    ta.d[9] = {fc2_w, fc2_t, 2048, 256};
    transpose_cvt<<<dim3(512, 10), 256, 0, stream>>>(ta);

    auto gemm_grid = [](int M, int N) { return dim3((M / 128) * (N / 64)); };

    // self-attention: fused QKV projection (A = vis f32, converted in-kernel)
    Slice sq = {q_bf, sa_bq, 1}, sk = {k_bf, sa_bk, 1}, sv = {vt_bf, sa_bv, 2};
    gemm_xproj<<<dim3((Mq / 128) * 12), 256, 0, stream>>>(vis, wqkv_t, sq, sk, sv, Mq, Mq / 128);
    attn_kernel<<<dim3(B * HEADS * (Sq / 64)), 256, 0, stream>>>(q_bf, k_bf, vt_bf, vmask, ctx_bf, Sq, Sq, Mq);
    gemm_bias<0, false><<<gemm_grid(Mq, 256), 256, 0, stream>>>(ctx_bf, wo_t, sa_bo, attn_f, Mq, 256, 256, Mq / 128);
    ln_kernel<false, true><<<dim3(Mq / 4), 256, 0, stream>>>(attn_f, vis, ln1_g, ln1_b, nullptr, nullptr, h1_f, h1_bf);

    // cross-attention: fused KV projection (A = txt f32), Q projection from h1
    Slice ck = {k_bf, ca_bk, 1}, cv = {vt_bf, ca_bv, 2}, cd = {nullptr, nullptr, 1};
    gemm_xproj<<<dim3((Mt / 128) * 8), 256, 0, stream>>>(txt, wkv_t, ck, cv, cd, Mt, Mt / 128);
    gemm_bias<1, false><<<gemm_grid(Mq, 256), 256, 0, stream>>>(h1_bf, cwq_t, ca_bq, q_bf, Mq, 256, 256, Mq / 128);
    attn_kernel<<<dim3(B * HEADS * (Sq / 64)), 256, 0, stream>>>(q_bf, k_bf, vt_bf, tmask, ctx_bf, Sq, St, Mt);
    gemm_bias<0, false><<<gemm_grid(Mq, 256), 256, 0, stream>>>(ctx_bf, cwo_t, ca_bo, attn_f, Mq, 256, 256, Mq / 128);
    ln_kernel<true, true><<<dim3(Mq / 4), 256, 0, stream>>>(attn_f, h1_f, ln2_g, ln2_b, ln3_g, ln3_b, h3_f, h3_bf);

    // FFN
    gemm_bias<1, true><<<gemm_grid(Mq, 2048), 256, 0, stream>>>(h3_bf, fc1_t, fc1_b, ffn1_bf, Mq, 2048, 256, Mq / 128);
    gemm_bias<0, false><<<gemm_grid(Mq, 256), 256, 0, stream>>>(ffn1_bf, fc2_t, fc2_b, ffn2_f, Mq, 256, 2048, Mq / 128);
    ln_kernel<false, false><<<dim3(Mq / 4), 256, 0, stream>>>(ffn2_f, h3_f, ln4_g, ln4_b, nullptr, nullptr, (float*)d_out, nullptr);
}

// Round 4
// 295.368 us; speedup vs baseline: 1.4213x; 1.3246x over previous
//
#include <hip/hip_runtime.h>
#include <stdint.h>
#include <stddef.h>

#define HEADS 8
#define DH 32
#define DMODEL 256
#define LN_EPS 1e-5f
#define QSCALE 0.17677669529663687f  // 1/sqrt(32), folded into Q projection

typedef unsigned short u16;
typedef __bf16 bf16x8 __attribute__((ext_vector_type(8)));
typedef unsigned short u16x8 __attribute__((ext_vector_type(8)));
typedef float f32x4 __attribute__((ext_vector_type(4)));

static __device__ __forceinline__ u16 bfc(float f) {          // hw cvt (RNE), pairs fuse to v_cvt_pk_bf16_f32
    return __builtin_bit_cast(u16, (__bf16)f);
}
static __device__ __forceinline__ bf16x8 ldbf8(const u16* p) {
    return __builtin_bit_cast(bf16x8, *reinterpret_cast<const u16x8*>(p));
}
static __device__ __forceinline__ bf16x8 cvt8(float4 a, float4 b) {
    bf16x8 r;
    r[0] = (__bf16)a.x; r[1] = (__bf16)a.y; r[2] = (__bf16)a.z; r[3] = (__bf16)a.w;
    r[4] = (__bf16)b.x; r[5] = (__bf16)b.y; r[6] = (__bf16)b.z; r[7] = (__bf16)b.w;
    return r;
}

// ---------------- batched transpose + convert: W[K][N] -> Wt[N][K] bf16 ----------------
struct TDesc { const float* src; u16* dst; int K; int N; };
struct TArgs { TDesc d[10]; };

__global__ __launch_bounds__(256) void transpose_cvt(TArgs args) {
    TDesc d = args.d[blockIdx.y];
    const int ntx = d.N >> 5;
    const int tiles = (d.K >> 5) * ntx;
    if ((int)blockIdx.x >= tiles) return;
    const int tk = (blockIdx.x / ntx) << 5;
    const int tn = (blockIdx.x % ntx) << 5;
    __shared__ float t[32][33];
    const int lx = threadIdx.x & 31;
    const int ly = threadIdx.x >> 5;
#pragma unroll
    for (int i = 0; i < 4; ++i)
        t[ly + 8 * i][lx] = d.src[(size_t)(tk + ly + 8 * i) * d.N + tn + lx];
    __syncthreads();
#pragma unroll
    for (int i = 0; i < 4; ++i)
        d.dst[(size_t)(tn + ly + 8 * i) * d.K + tk + lx] = bfc(t[lx][ly + 8 * i]);
}

// ---------------- fused projection GEMM: f32 A -> up to 3 output slices ----------------
struct Slice { u16* out; const float* bias; int mode; float sc; };

__global__ __launch_bounds__(256) void gemm_xproj(
    const float* __restrict__ Af, const u16* __restrict__ Wt,
    Slice s0, Slice s1, Slice s2, int M, int ntm)
{
    const int lane = threadIdx.x & 63;
    const int wave = threadIdx.x >> 6;
    const int l15 = lane & 15, lhi = lane >> 4;
    const int tm = ((int)blockIdx.x % ntm) * 128;
    const int tn = ((int)blockIdx.x / ntm) * 64;
    const int wm = tm + wave * 32;
    const int sel = tn >> 8;
    const int tl = tn & 255;
    Slice sl = (sel == 0) ? s0 : (sel == 1 ? s1 : s2);

    const f32x4 z4 = {0.f, 0.f, 0.f, 0.f};
    f32x4 acc[2][4];
#pragma unroll
    for (int i = 0; i < 2; ++i)
#pragma unroll
        for (int j = 0; j < 4; ++j) acc[i][j] = z4;

    const float* ar0 = Af + (size_t)(wm + l15) * 256 + lhi * 8;
    const float* ar1 = ar0 + (size_t)16 * 256;
    const u16* b0p = Wt + (size_t)(tn + l15) * 256 + lhi * 8;

    float4 a00 = *(const float4*)(ar0), a01 = *(const float4*)(ar0 + 4);
    float4 a10 = *(const float4*)(ar1), a11 = *(const float4*)(ar1 + 4);
    bf16x8 b[4];
#pragma unroll
    for (int j = 0; j < 4; ++j) b[j] = ldbf8(b0p + (size_t)j * 16 * 256);

#pragma unroll
    for (int k = 32; k < 256; k += 32) {
        float4 n00 = *(const float4*)(ar0 + k), n01 = *(const float4*)(ar0 + k + 4);
        float4 n10 = *(const float4*)(ar1 + k), n11 = *(const float4*)(ar1 + k + 4);
        bf16x8 bn[4];
#pragma unroll
        for (int j = 0; j < 4; ++j) bn[j] = ldbf8(b0p + (size_t)j * 16 * 256 + k);
        bf16x8 a0 = cvt8(a00, a01), a1 = cvt8(a10, a11);
#pragma unroll
        for (int j = 0; j < 4; ++j) {
            acc[0][j] = __builtin_amdgcn_mfma_f32_16x16x32_bf16(a0, b[j], acc[0][j], 0, 0, 0);
            acc[1][j] = __builtin_amdgcn_mfma_f32_16x16x32_bf16(a1, b[j], acc[1][j], 0, 0, 0);
        }
        a00 = n00; a01 = n01; a10 = n10; a11 = n11;
#pragma unroll
        for (int j = 0; j < 4; ++j) b[j] = bn[j];
    }
    {
        bf16x8 a0 = cvt8(a00, a01), a1 = cvt8(a10, a11);
#pragma unroll
        for (int j = 0; j < 4; ++j) {
            acc[0][j] = __builtin_amdgcn_mfma_f32_16x16x32_bf16(a0, b[j], acc[0][j], 0, 0, 0);
            acc[1][j] = __builtin_amdgcn_mfma_f32_16x16x32_bf16(a1, b[j], acc[1][j], 0, 0, 0);
        }
    }

#pragma unroll
    for (int i = 0; i < 2; ++i) {
#pragma unroll
        for (int j = 0; j < 4; ++j) {
            const int col = tl + j * 16 + l15;
            const float bv = sl.bias[col];
            const int row0 = wm + i * 16 + lhi * 4;
            if (sl.mode == 1) {
#pragma unroll
                for (int r = 0; r < 4; ++r)
                    sl.out[(size_t)(row0 + r) * 256 + col] = bfc((acc[i][j][r] + bv) * sl.sc);
            } else {
                ushort4 o = make_ushort4(bfc((acc[i][j][0] + bv) * sl.sc), bfc((acc[i][j][1] + bv) * sl.sc),
                                         bfc((acc[i][j][2] + bv) * sl.sc), bfc((acc[i][j][3] + bv) * sl.sc));
                *reinterpret_cast<ushort4*>(sl.out + (size_t)col * M + row0) = o;
            }
        }
    }
}

// ---------------- MFMA GEMM: C[M][N] = (A[M][K] @ B + bias) * osc ----------------
// MODE 0: f32 out [M][N].  MODE 1: bf16 out [M][N].
template<int MODE, bool RELU>
__global__ __launch_bounds__(256) void gemm_bias(
    const u16* __restrict__ A, const u16* __restrict__ Bt,
    const float* __restrict__ bias, void* __restrict__ Cout,
    int M, int N, int K, int ntm, float osc)
{
    const int lane = threadIdx.x & 63;
    const int wave = threadIdx.x >> 6;
    const int l15 = lane & 15, lhi = lane >> 4;
    const int tm = ((int)blockIdx.x % ntm) * 128;
    const int tn = ((int)blockIdx.x / ntm) * 64;
    const int wm = tm + wave * 32;

    const f32x4 z4 = {0.f, 0.f, 0.f, 0.f};
    f32x4 acc[2][4];
#pragma unroll
    for (int i = 0; i < 2; ++i)
#pragma unroll
        for (int j = 0; j < 4; ++j) acc[i][j] = z4;

    const u16* a0p = A + (size_t)(wm + l15) * K + lhi * 8;
    const u16* a1p = a0p + (size_t)16 * K;
    const u16* b0p = Bt + (size_t)(tn + l15) * K + lhi * 8;

    bf16x8 a0 = ldbf8(a0p), a1 = ldbf8(a1p);
    bf16x8 b[4];
#pragma unroll
    for (int j = 0; j < 4; ++j) b[j] = ldbf8(b0p + (size_t)j * 16 * K);

    for (int k = 32; k < K; k += 32) {
        bf16x8 a0n = ldbf8(a0p + k), a1n = ldbf8(a1p + k);
        bf16x8 bn[4];
#pragma unroll
        for (int j = 0; j < 4; ++j) bn[j] = ldbf8(b0p + (size_t)j * 16 * K + k);
#pragma unroll
        for (int j = 0; j < 4; ++j) {
            acc[0][j] = __builtin_amdgcn_mfma_f32_16x16x32_bf16(a0, b[j], acc[0][j], 0, 0, 0);
            acc[1][j] = __builtin_amdgcn_mfma_f32_16x16x32_bf16(a1, b[j], acc[1][j], 0, 0, 0);
        }
        a0 = a0n; a1 = a1n;
#pragma unroll
        for (int j = 0; j < 4; ++j) b[j] = bn[j];
    }
#pragma unroll
    for (int j = 0; j < 4; ++j) {
        acc[0][j] = __builtin_amdgcn_mfma_f32_16x16x32_bf16(a0, b[j], acc[0][j], 0, 0, 0);
        acc[1][j] = __builtin_amdgcn_mfma_f32_16x16x32_bf16(a1, b[j], acc[1][j], 0, 0, 0);
    }

#pragma unroll
    for (int i = 0; i < 2; ++i) {
#pragma unroll
        for (int j = 0; j < 4; ++j) {
            const int col = tn + j * 16 + l15;
            const float bv = bias[col];
            const int row0 = wm + i * 16 + lhi * 4;
            if (MODE == 0) {
                float* C = (float*)Cout;
#pragma unroll
                for (int r = 0; r < 4; ++r) {
                    float v = acc[i][j][r] + bv;
                    if (RELU) v = fmaxf(v, 0.f);
                    C[(size_t)(row0 + r) * N + col] = v;
                }
            } else {
                u16* C = (u16*)Cout;
#pragma unroll
                for (int r = 0; r < 4; ++r) {
                    float v = acc[i][j][r] + bv;
                    if (RELU) v = fmaxf(v, 0.f);
                    C[(size_t)(row0 + r) * N + col] = bfc(v * osc);
                }
            }
        }
    }
}

// ---------------- fused flash attention: swapped-QK^T, 32 q-rows/wave ----------------
// Qb pre-scaled by 1/sqrt(dh). Block = 4 waves x 32 rows = 128 q-rows. Grid = B*H*(Sq/128).
// Fast path has NO cross-lane reductions: per-lane partial max is a safe defer-max bound.
__global__ __launch_bounds__(256) void attn_kernel(
    const u16* __restrict__ Qb, const u16* __restrict__ Kb,
    const u16* __restrict__ Vt, const float* __restrict__ mask,
    u16* __restrict__ Ob, int Sq, int Sk, int MkTot)
{
    const int wave = threadIdx.x >> 6;
    const int lane = threadIdx.x & 63;
    const int l15 = lane & 15, lhi = lane >> 4;
    const int nqc = Sq >> 7;
    const int bh = blockIdx.x / nqc;
    const int qc = blockIdx.x % nqc;
    const int b = bh >> 3;
    const int h = bh & 7;
    const int colh = h * DH;
    const int qrow0 = b * Sq + (qc << 7) + wave * 32;
    const int swz = (l15 & 8) << 1;

    __shared__ __align__(16) u16 pt[4][32][72];   // 18KB, per-wave slices

    const f32x4 z4 = {0.f, 0.f, 0.f, 0.f};
    bf16x8 qf[2];
    qf[0] = ldbf8(Qb + (size_t)(qrow0 + l15) * DMODEL + colh + lhi * 8);
    qf[1] = ldbf8(Qb + (size_t)(qrow0 + 16 + l15) * DMODEL + colh + lhi * 8);

    f32x4 ctx[2][2] = {{z4, z4}, {z4, z4}};
    float m0 = -1e30f, m1 = -1e30f, ss0 = 0.f, ss1 = 0.f;

    const float* mb = mask + (size_t)b * Sk;
    const u16* kbase = Kb + (size_t)(b * Sk) * DMODEL + colh + lhi * 8;
    const u16* vbase = Vt + (size_t)colh * MkTot + (size_t)b * Sk;

    // preload tile 0 K/V/mask
    bf16x8 kf[4], vf[4];
    float4 mk[4];
#pragma unroll
    for (int j = 0; j < 4; ++j)
        kf[j] = ldbf8(kbase + (size_t)(j * 16 + l15) * DMODEL);
#pragma unroll
    for (int ks = 0; ks < 2; ++ks)
#pragma unroll
        for (int dt = 0; dt < 2; ++dt)
            vf[ks * 2 + dt] = ldbf8(vbase + (size_t)(dt * 16 + l15) * MkTot + ks * 32 + lhi * 8);
#pragma unroll
    for (int j = 0; j < 4; ++j)
        mk[j] = *reinterpret_cast<const float4*>(mb + j * 16 + lhi * 4);

    for (int kt = 0; kt < Sk; kt += 64) {
        // ---- S^T = K @ Q^T : 8 MFMAs ----
        f32x4 s[2][4];
        __builtin_amdgcn_s_setprio(1);
#pragma unroll
        for (int j = 0; j < 4; ++j) {
            s[0][j] = __builtin_amdgcn_mfma_f32_16x16x32_bf16(kf[j], qf[0], z4, 0, 0, 0);
            s[1][j] = __builtin_amdgcn_mfma_f32_16x16x32_bf16(kf[j], qf[1], z4, 0, 0, 0);
        }
        __builtin_amdgcn_s_setprio(0);

        // ---- prefetch next tile K/V/mask ----
        const int ktn = (kt + 64 < Sk) ? kt + 64 : kt;
        bf16x8 kn[4], vn[4];
        float4 mn[4];
#pragma unroll
        for (int j = 0; j < 4; ++j)
            kn[j] = ldbf8(kbase + (size_t)(ktn + j * 16 + l15) * DMODEL);
#pragma unroll
        for (int ks = 0; ks < 2; ++ks)
#pragma unroll
            for (int dt = 0; dt < 2; ++dt)
                vn[ks * 2 + dt] = ldbf8(vbase + (size_t)(dt * 16 + l15) * MkTot + ktn + ks * 32 + lhi * 8);
#pragma unroll
        for (int j = 0; j < 4; ++j)
            mn[j] = *reinterpret_cast<const float4*>(mb + ktn + j * 16 + lhi * 4);

        // ---- mask add (Q pre-scaled; mask shared across both row-groups) ----
#pragma unroll
        for (int j = 0; j < 4; ++j) {
            s[0][j][0] += mk[j].x; s[1][j][0] += mk[j].x;
            s[0][j][1] += mk[j].y; s[1][j][1] += mk[j].y;
            s[0][j][2] += mk[j].z; s[1][j][2] += mk[j].z;
            s[0][j][3] += mk[j].w; s[1][j][3] += mk[j].w;
        }

        // ---- per-lane partial max (NO shuffles in fast path) ----
        float mx0 = fmaxf(fmaxf(s[0][0][0], s[0][0][1]), fmaxf(s[0][0][2], s[0][0][3]));
        float mx1 = fmaxf(fmaxf(s[1][0][0], s[1][0][1]), fmaxf(s[1][0][2], s[1][0][3]));
#pragma unroll
        for (int j = 1; j < 4; ++j) {
            mx0 = fmaxf(mx0, fmaxf(fmaxf(s[0][j][0], s[0][j][1]), fmaxf(s[0][j][2], s[0][j][3])));
            mx1 = fmaxf(mx1, fmaxf(fmaxf(s[1][j][0], s[1][j][1]), fmaxf(s[1][j][2], s[1][j][3])));
        }

        // ---- defer-max trigger (rare): full reduce + rescale ----
        if (!__all((mx0 - m0 <= 8.0f) && (mx1 - m1 <= 8.0f))) {
            mx0 = fmaxf(mx0, __shfl_xor(mx0, 16, 64));
            mx0 = fmaxf(mx0, __shfl_xor(mx0, 32, 64));
            mx1 = fmaxf(mx1, __shfl_xor(mx1, 16, 64));
            mx1 = fmaxf(mx1, __shfl_xor(mx1, 32, 64));
            float n0 = fmaxf(m0, mx0), n1 = fmaxf(m1, mx1);
            float c0 = __expf(m0 - n0), c1 = __expf(m1 - n1);
            m0 = n0; m1 = n1; ss0 *= c0; ss1 *= c1;
#pragma unroll
            for (int r = 0; r < 4; ++r) {
                float cc0 = __shfl(c0, lhi * 4 + r, 64);
                float cc1 = __shfl(c1, lhi * 4 + r, 64);
                ctx[0][0][r] *= cc0; ctx[0][1][r] *= cc0;
                ctx[1][0][r] *= cc1; ctx[1][1][r] *= cc1;
            }
        }

        // ---- P = exp(S - m), lane-partial sums ----
        float ps0 = 0.f, ps1 = 0.f;
#pragma unroll
        for (int j = 0; j < 4; ++j)
#pragma unroll
            for (int r = 0; r < 4; ++r) {
                float p0 = __expf(s[0][j][r] - m0);
                float p1 = __expf(s[1][j][r] - m1);
                s[0][j][r] = p0; s[1][j][r] = p1;
                ps0 += p0; ps1 += p1;
            }
        ss0 += ps0; ss1 += ps1;

        // ---- P^T -> LDS (hw cvt_pk packs, swizzled b64 writes) ----
        asm volatile("" ::: "memory");
#pragma unroll
        for (int i = 0; i < 2; ++i)
#pragma unroll
            for (int j = 0; j < 4; ++j) {
                ushort4 w = make_ushort4(bfc(s[i][j][0]), bfc(s[i][j][1]),
                                         bfc(s[i][j][2]), bfc(s[i][j][3]));
                *reinterpret_cast<ushort4*>(&pt[wave][i * 16 + l15][(j * 16 + lhi * 4) ^ swz]) = w;
            }
        asm volatile("" ::: "memory");

        // ---- ctx += P @ V : 8 MFMAs ----
        __builtin_amdgcn_s_setprio(1);
#pragma unroll
        for (int ks = 0; ks < 2; ++ks) {
            bf16x8 pa0 = ldbf8(&pt[wave][l15][(ks * 32 + lhi * 8) ^ swz]);
            bf16x8 pa1 = ldbf8(&pt[wave][16 + l15][(ks * 32 + lhi * 8) ^ swz]);
#pragma unroll
            for (int dt = 0; dt < 2; ++dt) {
                ctx[0][dt] = __builtin_amdgcn_mfma_f32_16x16x32_bf16(pa0, vf[ks * 2 + dt], ctx[0][dt], 0, 0, 0);
                ctx[1][dt] = __builtin_amdgcn_mfma_f32_16x16x32_bf16(pa1, vf[ks * 2 + dt], ctx[1][dt], 0, 0, 0);
            }
        }
        __builtin_amdgcn_s_setprio(0);

#pragma unroll
        for (int j = 0; j < 4; ++j) { kf[j] = kn[j]; vf[j] = vn[j]; mk[j] = mn[j]; }
    }

    // ---- epilogue: reduce sums, divide, store ----
    ss0 += __shfl_xor(ss0, 16, 64); ss0 += __shfl_xor(ss0, 32, 64);
    ss1 += __shfl_xor(ss1, 16, 64); ss1 += __shfl_xor(ss1, 32, 64);
#pragma unroll
    for (int r = 0; r < 4; ++r) {
        const float i0 = 1.0f / __shfl(ss0, lhi * 4 + r, 64);
        const float i1 = 1.0f / __shfl(ss1, lhi * 4 + r, 64);
        const int row0 = qrow0 + lhi * 4 + r;
#pragma unroll
        for (int dt = 0; dt < 2; ++dt) {
            Ob[(size_t)row0 * DMODEL + colh + dt * 16 + l15] = bfc(ctx[0][dt][r] * i0);
            Ob[(size_t)(row0 + 16) * DMODEL + colh + dt * 16 + l15] = bfc(ctx[1][dt][r] * i1);
        }
    }
}

// ---------------- LayerNorm (fused residual add; optional second LN of 2*y) ----------------
template<bool DBL, bool WBF>
__global__ __launch_bounds__(256) void ln_kernel(
    const float* __restrict__ X, const float* __restrict__ Res,
    const float* __restrict__ g1p, const float* __restrict__ b1p,
    const float* __restrict__ g2p, const float* __restrict__ b2p,
    float* __restrict__ Of, u16* __restrict__ Oh)
{
    const int lane = threadIdx.x & 63;
    const int row = blockIdx.x * 4 + (threadIdx.x >> 6);
    const size_t base = (size_t)row * DMODEL + lane * 4;
    float4 x = *reinterpret_cast<const float4*>(X + base);
    float4 rr = *reinterpret_cast<const float4*>(Res + base);
    float v[4] = {x.x + rr.x, x.y + rr.y, x.z + rr.z, x.w + rr.w};
    float s = v[0] + v[1] + v[2] + v[3];
    float q = v[0] * v[0] + v[1] * v[1] + v[2] * v[2] + v[3] * v[3];
#pragma unroll
    for (int m = 1; m < 64; m <<= 1) { s += __shfl_xor(s, m, 64); q += __shfl_xor(q, m, 64); }
    float mean = s * (1.0f / DMODEL);
    float rstd = rsqrtf(fmaxf(q * (1.0f / DMODEL) - mean * mean, 0.f) + LN_EPS);
    float4 g = *reinterpret_cast<const float4*>(g1p + lane * 4);
    float4 bb = *reinterpret_cast<const float4*>(b1p + lane * 4);
    float y[4];
    y[0] = (v[0] - mean) * rstd * g.x + bb.x;
    y[1] = (v[1] - mean) * rstd * g.y + bb.y;
    y[2] = (v[2] - mean) * rstd * g.z + bb.z;
    y[3] = (v[3] - mean) * rstd * g.w + bb.w;
    if constexpr (DBL) {
#pragma unroll
        for (int k2 = 0; k2 < 4; ++k2) y[k2] *= 2.0f;
        float s2 = y[0] + y[1] + y[2] + y[3];
        float q2 = y[0] * y[0] + y[1] * y[1] + y[2] * y[2] + y[3] * y[3];
#pragma unroll
        for (int m = 1; m < 64; m <<= 1) { s2 += __shfl_xor(s2, m, 64); q2 += __shfl_xor(q2, m, 64); }
        float mean2 = s2 * (1.0f / DMODEL);
        float rstd2 = rsqrtf(fmaxf(q2 * (1.0f / DMODEL) - mean2 * mean2, 0.f) + LN_EPS);
        float4 g2 = *reinterpret_cast<const float4*>(g2p + lane * 4);
        float4 b2 = *reinterpret_cast<const float4*>(b2p + lane * 4);
        y[0] = (y[0] - mean2) * rstd2 * g2.x + b2.x;
        y[1] = (y[1] - mean2) * rstd2 * g2.y + b2.y;
        y[2] = (y[2] - mean2) * rstd2 * g2.z + b2.z;
        y[3] = (y[3] - mean2) * rstd2 * g2.w + b2.w;
    }
    *reinterpret_cast<float4*>(Of + base) = make_float4(y[0], y[1], y[2], y[3]);
    if constexpr (WBF) {
        ushort4 o = make_ushort4(bfc(y[0]), bfc(y[1]), bfc(y[2]), bfc(y[3]));
        *reinterpret_cast<ushort4*>(Oh + base) = o;
    }
}

// ---------------- host-side orchestration ----------------
extern "C" void kernel_launch(void* const* d_in, const int* in_sizes, int n_in,
                              void* d_out, int out_size, void* d_ws, size_t ws_size,
                              hipStream_t stream) {
    constexpr size_t MB = 1u << 20;
    if (ws_size < 70 * MB) return;

    const float* vis   = (const float*)d_in[0];
    const float* txt   = (const float*)d_in[1];
    const float* vmask = (const float*)d_in[2];
    const float* tmask = (const float*)d_in[3];
    const float* sa_wq = (const float*)d_in[4];  const float* sa_bq = (const float*)d_in[5];
    const float* sa_wk = (const float*)d_in[6];  const float* sa_bk = (const float*)d_in[7];
    const float* sa_wv = (const float*)d_in[8];  const float* sa_bv = (const float*)d_in[9];
    const float* sa_wo = (const float*)d_in[10]; const float* sa_bo = (const float*)d_in[11];
    const float* ca_wq = (const float*)d_in[12]; const float* ca_bq = (const float*)d_in[13];
    const float* ca_wk = (const float*)d_in[14]; const float* ca_bk = (const float*)d_in[15];
    const float* ca_wv = (const float*)d_in[16]; const float* ca_bv = (const float*)d_in[17];
    const float* ca_wo = (const float*)d_in[18]; const float* ca_bo = (const float*)d_in[19];
    const float* ln1_g = (const float*)d_in[20]; const float* ln1_b = (const float*)d_in[21];
    const float* ln2_g = (const float*)d_in[22]; const float* ln2_b = (const float*)d_in[23];
    const float* ln3_g = (const float*)d_in[24]; const float* ln3_b = (const float*)d_in[25];
    const float* ln4_g = (const float*)d_in[26]; const float* ln4_b = (const float*)d_in[27];
    const float* fc1_w = (const float*)d_in[28]; const float* fc1_b = (const float*)d_in[29];
    const float* fc2_w = (const float*)d_in[30]; const float* fc2_b = (const float*)d_in[31];

    const int B = 4, Sq = 2048, St = 1024;
    const int Mq = B * Sq;   // 8192
    const int Mt = B * St;   // 4096

    char* ws = (char*)d_ws;
    u16*   q_bf    = (u16*)(ws + 6 * MB);
    u16*   k_bf    = (u16*)(ws + 10 * MB);
    u16*   vt_bf   = (u16*)(ws + 14 * MB);
    u16*   ctx_bf  = (u16*)(ws + 18 * MB);
    u16*   ffn1_bf = (u16*)(ws + 0);          // 32MB, overlaps (dead by FFN)
    float* attn_f  = (float*)(ws + 32 * MB);
    float* h1_f    = (float*)(ws + 40 * MB);
    u16*   h1_bf   = (u16*)(ws + 48 * MB);
    float* h3_f    = (float*)(ws + 52 * MB);
    u16*   h3_bf   = (u16*)(ws + 60 * MB);
    u16*   wts     = (u16*)(ws + 64 * MB);
    float* ffn2_f  = attn_f;

    u16* wqkv_t = wts;                        // [768][256]
    u16* wkv_t  = wqkv_t + 768 * 256;         // [512][256]
    u16* cwq_t  = wkv_t + 512 * 256;
    u16* wo_t   = cwq_t + 65536;
    u16* cwo_t  = wo_t + 65536;
    u16* fc1_t  = cwo_t + 65536;              // [2048][256]
    u16* fc2_t  = fc1_t + 2048 * 256;         // [256][2048]

    TArgs ta;
    ta.d[0] = {sa_wq, wqkv_t + 0 * 65536, 256, 256};
    ta.d[1] = {sa_wk, wqkv_t + 1 * 65536, 256, 256};
    ta.d[2] = {sa_wv, wqkv_t + 2 * 65536, 256, 256};
    ta.d[3] = {ca_wk, wkv_t + 0 * 65536, 256, 256};
    ta.d[4] = {ca_wv, wkv_t + 1 * 65536, 256, 256};
    ta.d[5] = {ca_wq, cwq_t, 256, 256};
    ta.d[6] = {sa_wo, wo_t, 256, 256};
    ta.d[7] = {ca_wo, cwo_t, 256, 256};
    ta.d[8] = {fc1_w, fc1_t, 256, 2048};
    ta.d[9] = {fc2_w, fc2_t, 2048, 256};
    transpose_cvt<<<dim3(512, 10), 256, 0, stream>>>(ta);

    auto gemm_grid = [](int M, int N) { return dim3((M / 128) * (N / 64)); };

    // self-attention: fused QKV projection (Q pre-scaled by 1/sqrt(dh))
    Slice sq = {q_bf, sa_bq, 1, QSCALE}, sk = {k_bf, sa_bk, 1, 1.f}, sv = {vt_bf, sa_bv, 2, 1.f};
    gemm_xproj<<<dim3((Mq / 128) * 12), 256, 0, stream>>>(vis, wqkv_t, sq, sk, sv, Mq, Mq / 128);
    attn_kernel<<<dim3(B * HEADS * (Sq / 128)), 256, 0, stream>>>(q_bf, k_bf, vt_bf, vmask, ctx_bf, Sq, Sq, Mq);
    gemm_bias<0, false><<<gemm_grid(Mq, 256), 256, 0, stream>>>(ctx_bf, wo_t, sa_bo, attn_f, Mq, 256, 256, Mq / 128, 1.f);
    ln_kernel<false, true><<<dim3(Mq / 4), 256, 0, stream>>>(attn_f, vis, ln1_g, ln1_b, nullptr, nullptr, h1_f, h1_bf);

    // cross-attention
    Slice ck = {k_bf, ca_bk, 1, 1.f}, cv = {vt_bf, ca_bv, 2, 1.f}, cd = {nullptr, nullptr, 1, 1.f};
    gemm_xproj<<<dim3((Mt / 128) * 8), 256, 0, stream>>>(txt, wkv_t, ck, cv, cd, Mt, Mt / 128);
    gemm_bias<1, false><<<gemm_grid(Mq, 256), 256, 0, stream>>>(h1_bf, cwq_t, ca_bq, q_bf, Mq, 256, 256, Mq / 128, QSCALE);
    attn_kernel<<<dim3(B * HEADS * (Sq / 128)), 256, 0, stream>>>(q_bf, k_bf, vt_bf, tmask, ctx_bf, Sq, St, Mt);
    gemm_bias<0, false><<<gemm_grid(Mq, 256), 256, 0, stream>>>(ctx_bf, cwo_t, ca_bo, attn_f, Mq, 256, 256, Mq / 128, 1.f);
    ln_kernel<true, true><<<dim3(Mq / 4), 256, 0, stream>>>(attn_f, h1_f, ln2_g, ln2_b, ln3_g, ln3_b, h3_f, h3_bf);

    // FFN
    gemm_bias<1, true><<<gemm_grid(Mq, 2048), 256, 0, stream>>>(h3_bf, fc1_t, fc1_b, ffn1_bf, Mq, 2048, 256, Mq / 128, 1.f);
    gemm_bias<0, false><<<gemm_grid(Mq, 256), 256, 0, stream>>>(ffn1_bf, fc2_t, fc2_b, ffn2_f, Mq, 256, 2048, Mq / 128, 1.f);
    ln_kernel<false, false><<<dim3(Mq / 4), 256, 0, stream>>>(ffn2_f, h3_f, ln4_g, ln4_b, nullptr, nullptr, (float*)d_out, nullptr);
}